// Round 19
// baseline (71.390 us; speedup 1.0000x reference)
//
#include <hip/hip_runtime.h>

// SSIM fused: [16,1,1024,1024] fp32, 11-tap separable Gaussian.
// TWO independent tiles per wave (ILP-for-TLP): same img/tx, rows gy*32 and
// (gy+16)*32. Per stage: V_A, V_B (VALU overlaps slab-A ds_write drain),
// prefetch A+B (VMEM hides under H), H_A, H_B (B's reads overlap A's FMAs).
// Per tile: 64-col x 32-row, register ring of 11 packed f4 channels
// {a,b,a^2+b^2,ab}; H mapping q=lane>>3, run=lane&7, S0 = run<7 ? 7run : 47
// (slot-stride 7 -> 28r mod 32 covers all bank groups, conflict-free).
// Barrier-free (intra-wave DS ordering is HW-guaranteed). Scalar f4 math
// (r18: pk ops cost identical VALU cycles). No launch_bounds cap (r5/r6).
// Deterministic reduction: per-wave partial -> finalize kernel -> d_out[0].

typedef float f4 __attribute__((ext_vector_type(4)));

#define W      1024
#define H      1024
#define NIMG   16
#define HALO   5
#define TW     64                  // input cols per tile (LDS slots)
#define TOW    54                  // output cols per tile
#define RPS    8                   // rows per stage
#define NSTG   4                   // stages per tile
#define TH     (RPS*NSTG)          // 32 output rows per tile
#define NTX    19                  // ceil(1024/54)
#define NTYH   16                  // tile-pair rows: gy in [0,16), pair at gy+16
#define NSLOT  (NTX*NTYH*NIMG)     // 4864 wave slots (2 tiles each)
#define WPB    2                   // waves per block
#define BX     (WPB*64)            // 128 threads
#define NBLK   (NSLOT/WPB)         // 2432

template<bool INT>
__device__ __forceinline__ void pf_row(const float* __restrict__ p1,
                                       const float* __restrict__ p2,
                                       int j, int c, bool cOK,
                                       float& a, float& b)
{
    if (INT) {
        a = p1[(size_t)j * W + c];
        b = p2[(size_t)j * W + c];
    } else {
        const bool ok = cOK && ((unsigned)j < H);
        a = ok ? p1[(size_t)j * W + c] : 0.0f;
        b = ok ? p2[(size_t)j * W + c] : 0.0f;
    }
}

__device__ __forceinline__ f4 pack_ch(float a, float b)
{
    f4 v;
    v.x = a; v.y = b;
    v.z = fmaf(a, a, b * b);
    v.w = a * b;
    return v;
}

// V-blur RPS rows from prefetched registers into the tile's slab.
__device__ __forceinline__ void vstage(const float* __restrict__ w,
                                       const float (&pa)[RPS], const float (&pb)[RPS],
                                       f4 (&ring)[11], f4 (*slab)[TW], int lane)
{
#pragma unroll
    for (int rr = 0; rr < RPS; ++rr) {
#pragma unroll
        for (int k = 0; k < 10; ++k) ring[k] = ring[k + 1];
        ring[10] = pack_ch(pa[rr], pb[rr]);

        f4 acc = w[5] * ring[5];
#pragma unroll
        for (int k = 0; k < 5; ++k)
            acc += w[k] * (ring[k] + ring[10 - k]);

        slab[rr][lane] = acc;
    }
}

// H-blur of one staged stage; returns this lane's SSIM partial sum.
template<bool INT>
__device__ __forceinline__ float hstage(const float* __restrict__ w,
                                        const f4 (*slab)[TW],
                                        int q, int run, int S0, int obase)
{
    f4 o[7] = {};
#pragma unroll
    for (int i = 0; i < 17; ++i) {               // S0+16 <= 63: no clamp
        const f4 u = slab[q][S0 + i];
#pragma unroll
        for (int oo = 0; oo < 7; ++oo) {
            const int k = i - oo;
            if (k >= 0 && k < 11)
                o[oo] += w[k] * u;
        }
    }

    float s = 0.0f;
    const float C1f = 0.0001f, C2f = 0.0009f;
#pragma unroll
    for (int oo = 0; oo < 7; ++oo) {
        const int rel = S0 + oo;
        // run 7 re-covers run 6's cols at oo<2 -> mask those
        const bool valid = ((run < 7) || (oo >= 2)) &&
                           (INT || (obase + rel) < W);
        if (valid) {
            const float m1 = o[oo].x, m2 = o[oo].y;
            const float qq = o[oo].z, pp = o[oo].w;
            const float mu12 = m1 * m2, m1s = m1 * m1, m2s = m2 * m2;
            const float s12 = pp - mu12;
            const float ssq = qq - m1s - m2s;
            const float num = (2.f * mu12 + C1f) * (2.f * s12 + C2f);
            const float den = (m1s + m2s + C1f) * (ssq + C2f);
            s += num * __builtin_amdgcn_rcpf(den);
        }
    }
    return s;
}

template<bool INT>
__device__ float wave_pair(const float* __restrict__ p1,
                           const float* __restrict__ p2,
                           const float* __restrict__ w,
                           int cb, int rA0, int rB0, int lane, int obase,
                           f4 (*slabA)[TW], f4 (*slabB)[TW])
{
    const int  c   = cb + lane;
    const bool cOK = INT || ((unsigned)c < W);

    // rings: rows r0-5 .. r0+4 for each tile
    f4 ringA[11], ringB[11];
#pragma unroll
    for (int k = 0; k < 10; ++k) {
        float a, b;
        pf_row<INT>(p1, p2, rA0 - HALO + k, c, cOK, a, b);
        ringA[k + 1] = pack_ch(a, b);
        pf_row<INT>(p1, p2, rB0 - HALO + k, c, cOK, a, b);
        ringB[k + 1] = pack_ch(a, b);
    }

    const int q   = lane >> 3;
    const int run = lane & 7;
    const int S0  = (run < 7) ? 7 * run : 47;

    // prefetch stage 0 for both tiles
    float paA[RPS], pbA[RPS], paB[RPS], pbB[RPS];
#pragma unroll
    for (int rr = 0; rr < RPS; ++rr) {
        pf_row<INT>(p1, p2, rA0 + HALO + rr, c, cOK, paA[rr], pbA[rr]);
        pf_row<INT>(p1, p2, rB0 + HALO + rr, c, cOK, paB[rr], pbB[rr]);
    }

    float tsum = 0.0f;

    for (int st = 0; st < NSTG; ++st) {
        // V phases: B's ring math overlaps A's ds_write drain
        vstage(w, paA, pbA, ringA, slabA, lane);
        vstage(w, paB, pbB, ringB, slabB, lane);

        // prefetch next stage (VMEM latency hides under both H phases)
        if (st + 1 < NSTG) {
#pragma unroll
            for (int rr = 0; rr < RPS; ++rr) {
                pf_row<INT>(p1, p2, rA0 + (st + 1) * RPS + HALO + rr, c, cOK,
                            paA[rr], pbA[rr]);
                pf_row<INT>(p1, p2, rB0 + (st + 1) * RPS + HALO + rr, c, cOK,
                            paB[rr], pbB[rr]);
            }
        }

        // H phases: B's ds_reads overlap A's FMA tail
        tsum += hstage<INT>(w, slabA, q, run, S0, obase);
        tsum += hstage<INT>(w, slabB, q, run, S0, obase);
    }
    return tsum;
}

__global__ __launch_bounds__(BX) void ssim_main(const float* __restrict__ img1,
                                                const float* __restrict__ img2,
                                                const float* __restrict__ win,
                                                float* __restrict__ partials)
{
    __shared__ f4 lds[WPB][2][RPS][TW];      // 2 waves x 2 x 8 KB slabs = 32 KB

    const int t    = threadIdx.x;
    const int wid  = t >> 6;
    const int lane = t & 63;
    const int gw   = blockIdx.x * WPB + wid; // wave slot

    // slot -> (img, gyA, tx); tx fastest for L2 halo sharing
    const int img = gw / (NTX * NTYH);
    const int rem = gw - img * (NTX * NTYH);
    const int gyA = rem / NTX;
    const int tx  = rem - gyA * NTX;

    const int cb    = tx * TOW - HALO;
    const int obase = tx * TOW;
    const int rA0   = gyA * TH;              // tile A rows
    const int rB0   = rA0 + NTYH * TH;       // tile B rows (+512)

    const float* __restrict__ p1 = img1 + (size_t)img * (size_t)(W * H);
    const float* __restrict__ p2 = img2 + (size_t)img * (size_t)(W * H);

    float w[11];
#pragma unroll
    for (int k = 0; k < 11; ++k)
        w[k] = __int_as_float(__builtin_amdgcn_readfirstlane(__float_as_int(win[k])));

    const bool interior = (cb >= 0) && (cb + TW <= W) &&
                          (rA0 >= HALO) && (rB0 + TH - 1 + HALO < H);

    float tsum = interior
               ? wave_pair<true >(p1, p2, w, cb, rA0, rB0, lane, obase,
                                  lds[wid][0], lds[wid][1])
               : wave_pair<false>(p1, p2, w, cb, rA0, rB0, lane, obase,
                                  lds[wid][0], lds[wid][1]);

    // wave-private reduction; one store per wave — no barrier
#pragma unroll
    for (int off = 32; off > 0; off >>= 1)
        tsum += __shfl_down(tsum, off, 64);

    if (lane == 0)
        partials[gw] = tsum;
}

__global__ __launch_bounds__(256) void ssim_finalize(const float* __restrict__ partials,
                                                     float* __restrict__ out)
{
    double s = 0.0;
    for (int i = threadIdx.x; i < NSLOT; i += 256) s += (double)partials[i];
#pragma unroll
    for (int off = 32; off > 0; off >>= 1)
        s += __shfl_down(s, off, 64);

    __shared__ double ws[4];
    if ((threadIdx.x & 63) == 0) ws[threadIdx.x >> 6] = s;
    __syncthreads();
    if (threadIdx.x == 0) {
        const double tt = ws[0] + ws[1] + ws[2] + ws[3];
        out[0] = (float)(tt / (double)((size_t)NIMG * W * H));
    }
}

extern "C" void kernel_launch(void* const* d_in, const int* in_sizes, int n_in,
                              void* d_out, int out_size, void* d_ws, size_t ws_size,
                              hipStream_t stream)
{
    const float* img1 = (const float*)d_in[0];
    const float* img2 = (const float*)d_in[1];
    const float* win  = (const float*)d_in[2];
    float* partials   = (float*)d_ws;
    float* out        = (float*)d_out;

    ssim_main<<<NBLK, BX, 0, stream>>>(img1, img2, win, partials);
    ssim_finalize<<<1, 256, 0, stream>>>(partials, out);
}